// Round 1
// baseline (1037.473 us; speedup 1.0000x reference)
//
#include <hip/hip_runtime.h>

// SparseBlock Conv2d+BN+ReLU. N=2, CIN=COUT=64, H=W=768, K=3, pad=1,
// 256 active 48x48 blocks (stride 48), output zeroed elsewhere.
//
// R1 vs baseline (582us total / main 209us):
//  - staging via global_load_lds DMA (fire-and-forget) into f32 slot buffer,
//    then LDS-local convert phase (f32->bf16). Removes the per-chunk
//    global->reg->LDS round trip + vmcnt register dependency.
//  - bank-conflict fix: bf16 tile in 16B units u = r*57 + c + (c>>3)
//    (write pattern spreads across all 8 bank groups; reads stay ~2-way).
//  - __launch_bounds__(512,8) to force <=64 VGPR / 4 WGs/CU.

typedef __attribute__((ext_vector_type(8))) short short8;
typedef __attribute__((ext_vector_type(4))) float floatx4;

// ws layout (float slots):
// [0,64)    scale
// [64,128)  shift
// [128,640) flags (512 ints)
// [640,..)  wa: 49152 bf16 A-frag weights: [ks=cc*3+kt][cout][quad(tap)][j(ci8)]
#define WS_SCALE 0
#define WS_SHIFT 64
#define WS_FLAGS 128
#define WS_WA    640

#define CONV_WGS 1536   // 256 blocks * 6 strips
#define ZERO_WGS 4096   // 512 tiles * 8 channel-parts

__device__ __forceinline__ short f2bf(float f) {
  unsigned u = __builtin_bit_cast(unsigned, f);
  u += 0x7fffu + ((u >> 16) & 1u);
  return (short)(u >> 16);
}

__device__ __forceinline__ void gload_lds16(const float* g, float* l) {
  __builtin_amdgcn_global_load_lds(
      (const __attribute__((address_space(1))) void*)g,
      (__attribute__((address_space(3))) void*)l, 16, 0, 0);
}

__global__ __launch_bounds__(256) void prep_kernel(
    const float* __restrict__ conv_w,
    const float* __restrict__ conv_b,
    const float* __restrict__ gamma,
    const float* __restrict__ beta,
    const float* __restrict__ run_mean,
    const float* __restrict__ run_var,
    const int* __restrict__ abi,
    float* __restrict__ ws) {
  int tid = threadIdx.x;
  if (blockIdx.x == 0) {
    int* flags = (int*)(ws + WS_FLAGS);
    flags[tid] = 0;
    flags[tid + 256] = 0;
    __syncthreads();
    int n = abi[3 * tid + 0];
    int bh = abi[3 * tid + 1];
    int bw = abi[3 * tid + 2];
    flags[n * 256 + bh * 16 + bw] = 1;
    if (tid < 64) {
      float inv = gamma[tid] * rsqrtf(run_var[tid] + 1e-3f);
      ws[WS_SCALE + tid] = inv;
      ws[WS_SHIFT + tid] = (conv_b[tid] - run_mean[tid]) * inv + beta[tid];
    }
  }
  // A-frag weight pack: wa[((ks*64 + cout)*4 + q)*8 + j]
  //   ks = cc*3+kt; tap = kt*4+q; element = w[cout][ci=cc*8+j][tap] or 0 (pad)
  short* wa = (short*)(ws + WS_WA);
  for (int d = blockIdx.x * 256 + tid; d < 49152; d += 64 * 256) {
    int j = d & 7;
    int q = (d >> 3) & 3;
    int cout = (d >> 5) & 63;
    int ks = d >> 11;          // 0..23
    int kt = ks % 3;
    int cc = ks / 3;
    int tap = kt * 4 + q;
    short v = 0;
    if (tap < 9) {
      int ci = cc * 8 + j;
      int dy = tap / 3;
      int dx = tap - dy * 3;
      v = f2bf(conv_w[((cout * 64 + ci) * 3 + dy) * 3 + dx]);
    }
    wa[d] = v;
  }
}

// Merged conv + zero kernel. 512 threads.
__global__ __launch_bounds__(512, 8) void main_kernel(
    const float* __restrict__ x,
    const float* __restrict__ ws_f,
    const int* __restrict__ abi,
    float* __restrict__ out) {
  // f32 DMA landing buffer: 1152 slots x 16B (slot = (ci*10+r)*14+f, pad>=1120)
  __shared__ __align__(16) float Fs[4608];
  // bf16 compute tiles, skewed: unit u(r,c) = r*57 + c + (c>>3), short idx u*8+ci
  // 608 units each; zero units at u=570,588,606 (pad taps, +c16*288 bytes).
  __shared__ __align__(16) short bfb[2][4864];

  int b = blockIdx.x;
  int tid = threadIdx.x;

  if (b >= CONV_WGS) {
    // ---- zero path: inactive tiles ----
    const int* flags = (const int*)(ws_f + WS_FLAGS);
    int z = b - CONV_WGS;
    int tile = z >> 3;
    int part = z & 7;
    if (flags[tile]) return;
    int n = tile >> 8;
    int bh = (tile >> 4) & 15;
    int bw = tile & 15;
    float* base = out + (((n * 64 + part * 8) * 768 + bh * 48)) * 768 + bw * 48;
    float4 zv = make_float4(0.f, 0.f, 0.f, 0.f);
#pragma unroll
    for (int i = 0; i < 9; ++i) {        // 8ch*48r*12f4 = 4608
      int idx = i * 512 + tid;
      int f = idx % 12;
      int t2 = idx / 12;
      int rr = t2 % 48;
      int c = t2 / 48;                    // 0..7
      *((float4*)(base + (c * 768 + rr) * (size_t)768) + f) = zv;
    }
    return;
  }

  // ---- conv path ----
  int blk = b / 6;
  int strip = b - blk * 6;
  int n = abi[3 * blk + 0];
  int bh = abi[3 * blk + 1];
  int bw = abi[3 * blk + 2];
  int h0 = bh * 48 + strip * 8;   // output rows h0..h0+7
  int w0 = bw * 48;

  int lane = tid & 63;
  int wv = tid >> 6;              // wave 0..7 -> output row h0+wv
  int ln15 = lane & 15;
  int quad = lane >> 4;

  const float* xn = x + (size_t)n * 64 * 768 * 768;
  const short* wa = (const short*)(ws_f + WS_WA);
  const short* wap = wa + ln15 * 32 + quad * 8;

  // zero units for padded taps (u=570,588,606) in both buffers
  if (tid < 8) {
    bfb[0][4560 + tid] = 0; bfb[0][4704 + tid] = 0; bfb[0][4848 + tid] = 0;
    bfb[1][4560 + tid] = 0; bfb[1][4704 + tid] = 0; bfb[1][4848 + tid] = 0;
  }

  // per-lane B-frag byte base per kt; +c16*288 walks c16 (u(c+16)=u(c)+18 exactly)
  int bA[3];
#pragma unroll
  for (int kt = 0; kt < 3; ++kt) {
    int tap = kt * 4 + quad;
    if (tap < 9) {
      int dy = tap / 3;
      int dx = tap - dy * 3;
      int cx = ln15 + dx;                       // 0..17 (c16=0 base)
      bA[kt] = ((wv + dy) * 57 + cx + (cx >> 3)) * 16;
    } else {
      bA[kt] = 9120;                            // unit 570 (zeros); +288 -> 588,606
    }
  }

  // DMA one 16B slot of chunk c (ci-group base c*8) into Fs.
  // slot s -> ci=s/140, r=(s%140)/14, f=s%14; gh=h0-1+r; gw0=w0-4+4f.
  // Every f4 is fully in- or out-of-bounds (w0-4 multiple of 4).
  auto dma_slot = [&](int c, int s) {
    int ci = s / 140;
    int rem = s - ci * 140;
    int r = rem / 14;
    int f = rem - r * 14;
    int gh = h0 - 1 + r;
    int gw0 = w0 - 4 + 4 * f;
    const float* src = xn;                      // safe dummy for invalid slots
    if (s < 1120 && (unsigned)gh < 768u && (unsigned)gw0 <= 764u)
      src = xn + (size_t)c * (8 * 768 * 768) + ((size_t)ci * 768 + gh) * 768 + gw0;
    gload_lds16(src, &Fs[s * 4]);
  };
  auto dma_chunk = [&](int c) {
    dma_slot(c, tid);
    dma_slot(c, 512 + tid);
    if (wv < 2) dma_slot(c, 1024 + tid);        // slots 1024..1151 (>=1120 pad)
  };

  // LDS-local convert: Fs (f32) -> bfb[bsel] (bf16, skewed). Zero for OOB slots.
  auto convert = [&](int bsel) {
#pragma unroll
    for (int i = 0; i < 3; ++i) {
      int s = i * 512 + tid;
      if (i == 2 && s >= 1120) break;
      int ci = s / 140;
      int rem = s - ci * 140;
      int r = rem / 14;
      int f = rem - r * 14;
      bool ok = ((unsigned)(h0 - 1 + r) < 768u) && ((unsigned)(w0 - 4 + 4 * f) <= 764u);
      float4 v = *(const float4*)&Fs[s * 4];
      int cb = 4 * f - 3;
      int rb = r * 57;
#pragma unroll
      for (int j = 0; j < 4; ++j) {
        int cth = cb + j;
        if ((unsigned)cth < 50u) {
          int u = rb + cth + (cth >> 3);
          bfb[bsel][u * 8 + ci] = ok ? f2bf(((const float*)&v)[j]) : (short)0;
        }
      }
    }
  };

  floatx4 acc[3][4];
#pragma unroll
  for (int c16 = 0; c16 < 3; ++c16)
#pragma unroll
    for (int mt = 0; mt < 4; ++mt)
      acc[c16][mt] = (floatx4){0.f, 0.f, 0.f, 0.f};

  // prologue: chunk 0 -> Fs -> bfb[0]
  dma_chunk(0);
  __syncthreads();
  convert(0);
  __syncthreads();

  for (int cc = 0; cc < 8; ++cc) {
    int bsel = cc & 1;
    if (cc < 7) dma_chunk(cc + 1);              // fire-and-forget next chunk
    const char* lb = (const char*)bfb[bsel];
#pragma unroll
    for (int kt = 0; kt < 3; ++kt) {
      int ks = cc * 3 + kt;
      short8 af[4];
#pragma unroll
      for (int mt = 0; mt < 4; ++mt)
        af[mt] = *(const short8*)(wap + ks * 2048 + mt * 512);
#pragma unroll
      for (int c16 = 0; c16 < 3; ++c16) {
        short8 bf = *(const short8*)(lb + bA[kt] + c16 * 288);
#pragma unroll
        for (int mt = 0; mt < 4; ++mt)
          acc[c16][mt] = __builtin_amdgcn_mfma_f32_16x16x32_bf16(
              af[mt], bf, acc[c16][mt], 0, 0, 0);
      }
    }
    __syncthreads();                            // drains DMA(cc+1); bfb[bsel] reads done
    if (cc < 7) {
      convert(bsel ^ 1);                        // Fs -> bfb[next]
      __syncthreads();
    }
  }

  // ---- epilogue: BN fold + ReLU + store ----
  // D layout: row(m=cout within tile) = quad*4+reg, col(n=pixel) = ln15
  const float* scale = ws_f + WS_SCALE;
  const float* shift = ws_f + WS_SHIFT;
  float* op = out + (size_t)n * 64 * 768 * 768 + (size_t)(h0 + wv) * 768 + (w0 + ln15);
#pragma unroll
  for (int mt = 0; mt < 4; ++mt) {
#pragma unroll
    for (int reg = 0; reg < 4; ++reg) {
      int cout = mt * 16 + quad * 4 + reg;
      float sc = scale[cout];
      float sh = shift[cout];
#pragma unroll
      for (int c16 = 0; c16 < 3; ++c16) {
        float vv = fmaf(acc[c16][mt][reg], sc, sh);
        vv = vv > 0.f ? vv : 0.f;
        op[(size_t)cout * 589824 + c16 * 16] = vv;
      }
    }
  }
}

extern "C" void kernel_launch(void* const* d_in, const int* in_sizes, int n_in,
                              void* d_out, int out_size, void* d_ws, size_t ws_size,
                              hipStream_t stream) {
  const float* x = (const float*)d_in[0];
  const float* conv_w = (const float*)d_in[1];
  const float* conv_b = (const float*)d_in[2];
  const float* gamma = (const float*)d_in[3];
  const float* beta = (const float*)d_in[4];
  const float* run_mean = (const float*)d_in[5];
  const float* run_var = (const float*)d_in[6];
  const int* abi = (const int*)d_in[7];
  float* out = (float*)d_out;
  float* ws = (float*)d_ws;

  prep_kernel<<<64, 256, 0, stream>>>(conv_w, conv_b, gamma, beta,
                                      run_mean, run_var, abi, ws);
  main_kernel<<<CONV_WGS + ZERO_WGS, 512, 0, stream>>>(x, ws, abi, out);
}

// Round 2
// 617.096 us; speedup vs baseline: 1.6812x; 1.6812x over previous
//
#include <hip/hip_runtime.h>

// SparseBlock Conv2d+BN+ReLU. N=2, CIN=COUT=64, H=W=768, K=3, pad=1,
// 256 active 48x48 blocks (stride 48), output zeroed elsewhere.
//
// R2 = verified R0 structure (reg-staged, 1 barrier/chunk, lb(512,4)) plus:
//  - skewed bf16 LDS layout u = r*57 + c + (c>>3) (16B units) to kill the
//    ~7-way ds_write_b16 bank conflicts (1.3e7 conflict cycles in R0).
//  - Bresenham interleave of conv and zero workgroups so write-BW work
//    overlaps conv latency stalls instead of running as a separate phase.
// R1 lesson: __launch_bounds__(512,8) forced VGPR 32 -> scratch spill ->
// 5x fetch AND write amplification. Keep (512,4) / VGPR 64.

typedef __attribute__((ext_vector_type(8))) short short8;
typedef __attribute__((ext_vector_type(4))) float floatx4;

// ws layout (float slots):
// [0,64)    scale
// [64,128)  shift
// [128,640) flags (512 ints)
// [640,..)  wa: 49152 bf16 A-frag weights: [ks=cc*3+kt][cout][quad(tap)][j(ci8)]
#define WS_SCALE 0
#define WS_SHIFT 64
#define WS_FLAGS 128
#define WS_WA    640

#define CONV_WGS 1536   // 256 blocks * 6 strips
#define ZERO_WGS 4096   // 512 tiles * 8 channel-parts
#define TOTAL_WGS (CONV_WGS + ZERO_WGS)

__device__ __forceinline__ short f2bf(float f) {
  unsigned u = __builtin_bit_cast(unsigned, f);
  u += 0x7fffu + ((u >> 16) & 1u);
  return (short)(u >> 16);
}

__global__ __launch_bounds__(256) void prep_kernel(
    const float* __restrict__ conv_w,
    const float* __restrict__ conv_b,
    const float* __restrict__ gamma,
    const float* __restrict__ beta,
    const float* __restrict__ run_mean,
    const float* __restrict__ run_var,
    const int* __restrict__ abi,
    float* __restrict__ ws) {
  int tid = threadIdx.x;
  if (blockIdx.x == 0) {
    int* flags = (int*)(ws + WS_FLAGS);
    flags[tid] = 0;
    flags[tid + 256] = 0;
    __syncthreads();
    int n = abi[3 * tid + 0];
    int bh = abi[3 * tid + 1];
    int bw = abi[3 * tid + 2];
    flags[n * 256 + bh * 16 + bw] = 1;
    if (tid < 64) {
      float inv = gamma[tid] * rsqrtf(run_var[tid] + 1e-3f);
      ws[WS_SCALE + tid] = inv;
      ws[WS_SHIFT + tid] = (conv_b[tid] - run_mean[tid]) * inv + beta[tid];
    }
  }
  // A-frag weight pack: wa[((ks*64 + cout)*4 + q)*8 + j]
  //   ks = cc*3+kt; tap = kt*4+q; element = w[cout][ci=cc*8+j][tap] or 0 (pad)
  short* wa = (short*)(ws + WS_WA);
  for (int d = blockIdx.x * 256 + tid; d < 49152; d += 64 * 256) {
    int j = d & 7;
    int q = (d >> 3) & 3;
    int cout = (d >> 5) & 63;
    int ks = d >> 11;          // 0..23
    int kt = ks % 3;
    int cc = ks / 3;
    int tap = kt * 4 + q;
    short v = 0;
    if (tap < 9) {
      int ci = cc * 8 + j;
      int dy = tap / 3;
      int dx = tap - dy * 3;
      v = f2bf(conv_w[((cout * 64 + ci) * 3 + dy) * 3 + dx]);
    }
    wa[d] = v;
  }
}

// Merged conv + zero kernel. 512 threads.
__global__ __launch_bounds__(512, 4) void main_kernel(
    const float* __restrict__ x,
    const float* __restrict__ ws_f,
    const int* __restrict__ abi,
    float* __restrict__ out) {
  // bf16 tile, skewed 16B units: u(r,c) = r*57 + c + (c>>3); short idx u*8+ci.
  // Data units u<=568; zero units at u=570,588,606 serve padded taps
  // (bA pad base 570*16=9120, +c16*288 -> 588,606).
  __shared__ __align__(16) short lds[2][4864];

  int braw = blockIdx.x;
  int tid = threadIdx.x;

  // Bresenham interleave: conv wgs evenly spread through dispatch order.
  int before = (int)(((long long)braw * CONV_WGS) / TOTAL_WGS);
  int after  = (int)(((long long)(braw + 1) * CONV_WGS) / TOTAL_WGS);
  bool is_conv = after > before;

  if (!is_conv) {
    // ---- zero path: inactive tiles ----
    const int* flags = (const int*)(ws_f + WS_FLAGS);
    int z = braw - before;              // 0..4095, each exactly once
    int tile = z >> 3;
    int part = z & 7;
    if (flags[tile]) return;
    int n = tile >> 8;
    int bh = (tile >> 4) & 15;
    int bw = tile & 15;
    float* base = out + (((n * 64 + part * 8) * 768 + bh * 48)) * 768 + bw * 48;
    float4 zv = make_float4(0.f, 0.f, 0.f, 0.f);
#pragma unroll
    for (int i = 0; i < 9; ++i) {        // 8ch*48r*12f4 = 4608
      int idx = i * 512 + tid;
      int f = idx % 12;
      int t2 = idx / 12;
      int rr = t2 % 48;
      int c = t2 / 48;                    // 0..7
      *((float4*)(base + (c * 768 + rr) * (size_t)768) + f) = zv;
    }
    return;
  }

  // ---- conv path ----
  int b = before;                       // 0..1535
  int blk = b / 6;
  int strip = b - blk * 6;
  int n = abi[3 * blk + 0];
  int bh = abi[3 * blk + 1];
  int bw = abi[3 * blk + 2];
  int h0 = bh * 48 + strip * 8;   // output rows h0..h0+7
  int w0 = bw * 48;

  int lane = tid & 63;
  int wv = tid >> 6;              // wave 0..7 -> output row h0+wv
  int ln15 = lane & 15;
  int quad = lane >> 4;

  const float* xn = x + (size_t)n * 64 * 768 * 768;
  const short* wa = (const short*)(ws_f + WS_WA);
  const short* wap = wa + ln15 * 32 + quad * 8;

  // zero units for padded taps (u=570,588,606) in both buffers
  if (tid < 8) {
    lds[0][4560 + tid] = 0; lds[0][4704 + tid] = 0; lds[0][4848 + tid] = 0;
    lds[1][4560 + tid] = 0; lds[1][4704 + tid] = 0; lds[1][4848 + tid] = 0;
  }

  // per-lane B-frag byte base per kt; +c16*288 walks c16 (u(c+16)=u(c)+18)
  int bA[3];
#pragma unroll
  for (int kt = 0; kt < 3; ++kt) {
    int tap = kt * 4 + quad;
    if (tap < 9) {
      int dy = tap / 3;
      int dx = tap - dy * 3;
      int cx = ln15 + dx;                       // 0..17 (c16=0 base)
      bA[kt] = ((wv + dy) * 57 + cx + (cx >> 3)) * 16;
    } else {
      bA[kt] = 9120;                            // zero unit 570; +288 -> 588,606
    }
  }

  // stage decode: e -> (f:14, r:10, ci:8); gw window [w0-4, w0+52)
  auto load_chunk = [&](int cc8, float4* pf) {
#pragma unroll
    for (int i = 0; i < 3; ++i) {
      int e = i * 512 + tid;
      float4 v = make_float4(0.f, 0.f, 0.f, 0.f);
      if (e < 1120) {
        int f = e % 14;
        int t = e / 14;
        int r = t % 10;
        int ci = t / 10;
        int gh = h0 - 1 + r;
        int gw0 = w0 - 4 + 4 * f;
        if ((unsigned)gh < 768u) {
          const float* rp = xn + ((size_t)(cc8 + ci) * 768 + gh) * 768;
          if (gw0 >= 0 && gw0 <= 764) {
            v = *(const float4*)(rp + gw0);
          } else {
#pragma unroll
            for (int j = 0; j < 4; ++j) {
              int gw = gw0 + j;
              if ((unsigned)gw < 768u) ((float*)&v)[j] = rp[gw];
            }
          }
        }
      }
      pf[i] = v;
    }
  };
  auto store_chunk = [&](int bsel, const float4* pf) {
#pragma unroll
    for (int i = 0; i < 3; ++i) {
      int e = i * 512 + tid;
      if (e < 1120) {
        int f = e % 14;
        int t = e / 14;
        int r = t % 10;
        int ci = t / 10;
        const float* vp = (const float*)&pf[i];
#pragma unroll
        for (int j = 0; j < 4; ++j) {
          int c = 4 * f - 3 + j;
          if ((unsigned)c < 50u) {
            int u = r * 57 + c + (c >> 3);      // skewed unit
            lds[bsel][u * 8 + ci] = f2bf(vp[j]);
          }
        }
      }
    }
  };

  float4 pf[3];
  // prologue: stage chunk 0 into buf 0
  load_chunk(0, pf);
  store_chunk(0, pf);
  __syncthreads();

  floatx4 acc[3][4];
#pragma unroll
  for (int c16 = 0; c16 < 3; ++c16)
#pragma unroll
    for (int mt = 0; mt < 4; ++mt)
      acc[c16][mt] = (floatx4){0.f, 0.f, 0.f, 0.f};

  for (int cc = 0; cc < 8; ++cc) {
    int bsel = cc & 1;
    if (cc < 7) load_chunk((cc + 1) * 8, pf);   // prefetch next chunk
    const char* lb = (const char*)lds[bsel];
#pragma unroll
    for (int kt = 0; kt < 3; ++kt) {
      int ks = cc * 3 + kt;
      short8 af[4];
#pragma unroll
      for (int mt = 0; mt < 4; ++mt)
        af[mt] = *(const short8*)(wap + ks * 2048 + mt * 512);
#pragma unroll
      for (int c16 = 0; c16 < 3; ++c16) {
        short8 bf = *(const short8*)(lb + bA[kt] + c16 * 288);
#pragma unroll
        for (int mt = 0; mt < 4; ++mt)
          acc[c16][mt] = __builtin_amdgcn_mfma_f32_16x16x32_bf16(
              af[mt], bf, acc[c16][mt], 0, 0, 0);
      }
    }
    if (cc < 7) store_chunk(bsel ^ 1, pf);
    __syncthreads();
  }

  // ---- epilogue: BN fold + ReLU + store ----
  // D layout: row(m=cout within tile) = quad*4+reg, col(n=pixel) = ln15
  const float* scale = ws_f + WS_SCALE;
  const float* shift = ws_f + WS_SHIFT;
  float* op = out + (size_t)n * 64 * 768 * 768 + (size_t)(h0 + wv) * 768 + (w0 + ln15);
#pragma unroll
  for (int mt = 0; mt < 4; ++mt) {
#pragma unroll
    for (int reg = 0; reg < 4; ++reg) {
      int cout = mt * 16 + quad * 4 + reg;
      float sc = scale[cout];
      float sh = shift[cout];
#pragma unroll
      for (int c16 = 0; c16 < 3; ++c16) {
        float vv = fmaf(acc[c16][mt][reg], sc, sh);
        vv = vv > 0.f ? vv : 0.f;
        op[(size_t)cout * 589824 + c16 * 16] = vv;
      }
    }
  }
}

extern "C" void kernel_launch(void* const* d_in, const int* in_sizes, int n_in,
                              void* d_out, int out_size, void* d_ws, size_t ws_size,
                              hipStream_t stream) {
  const float* x = (const float*)d_in[0];
  const float* conv_w = (const float*)d_in[1];
  const float* conv_b = (const float*)d_in[2];
  const float* gamma = (const float*)d_in[3];
  const float* beta = (const float*)d_in[4];
  const float* run_mean = (const float*)d_in[5];
  const float* run_var = (const float*)d_in[6];
  const int* abi = (const int*)d_in[7];
  float* out = (float*)d_out;
  float* ws = (float*)d_ws;

  prep_kernel<<<64, 256, 0, stream>>>(conv_w, conv_b, gamma, beta,
                                      run_mean, run_var, abi, ws);
  main_kernel<<<TOTAL_WGS, 512, 0, stream>>>(x, ws, abi, out);
}

// Round 3
// 585.455 us; speedup vs baseline: 1.7721x; 1.0540x over previous
//
#include <hip/hip_runtime.h>

// SparseBlock Conv2d+BN+ReLU. N=2, CIN=COUT=64, H=W=768, K=3, pad=1,
// 256 active 48x48 blocks (stride 48), output zeroed elsewhere.
//
// R3 = R0 structure + skewed LDS (kept from R2) + 3-buffer/1-barrier
// software pipeline so the vmcnt wait for chunk cc+1 lands a full
// iteration after issue (HBM latency hidden; memory pipe stays fed).
// Dispatch order reverted to R0: conv wgs first (long pole), zero wgs
// backfill. R2 lesson: interleaving pushed conv starts into the tail
// (occupancy 42.7->35.8, BW 2.45->1.9 TB/s, dur +21%).
// R1 lesson: lb(512,8) forced VGPR 32 -> scratch spill -> 5x traffic.

typedef __attribute__((ext_vector_type(8))) short short8;
typedef __attribute__((ext_vector_type(4))) float floatx4;

// ws layout (float slots):
// [0,64)    scale
// [64,128)  shift
// [128,640) flags (512 ints)
// [640,..)  wa: 49152 bf16 A-frag weights: [ks=cc*3+kt][cout][quad(tap)][j(ci8)]
#define WS_SCALE 0
#define WS_SHIFT 64
#define WS_FLAGS 128
#define WS_WA    640

#define CONV_WGS 1536   // 256 blocks * 6 strips
#define ZERO_WGS 4096   // 512 tiles * 8 channel-parts

// skewed bf16 tile: 16B unit u(r,c) = r*57 + c + (c>>3); short idx u*8+ci.
// data units u<=568; zero units 570,588,606 serve padded taps.
#define LDS_BUF 4864    // shorts per buffer

__device__ __forceinline__ short f2bf(float f) {
  unsigned u = __builtin_bit_cast(unsigned, f);
  u += 0x7fffu + ((u >> 16) & 1u);
  return (short)(u >> 16);
}

__global__ __launch_bounds__(256) void prep_kernel(
    const float* __restrict__ conv_w,
    const float* __restrict__ conv_b,
    const float* __restrict__ gamma,
    const float* __restrict__ beta,
    const float* __restrict__ run_mean,
    const float* __restrict__ run_var,
    const int* __restrict__ abi,
    float* __restrict__ ws) {
  int tid = threadIdx.x;
  if (blockIdx.x == 0) {
    int* flags = (int*)(ws + WS_FLAGS);
    flags[tid] = 0;
    flags[tid + 256] = 0;
    __syncthreads();
    int n = abi[3 * tid + 0];
    int bh = abi[3 * tid + 1];
    int bw = abi[3 * tid + 2];
    flags[n * 256 + bh * 16 + bw] = 1;
    if (tid < 64) {
      float inv = gamma[tid] * rsqrtf(run_var[tid] + 1e-3f);
      ws[WS_SCALE + tid] = inv;
      ws[WS_SHIFT + tid] = (conv_b[tid] - run_mean[tid]) * inv + beta[tid];
    }
  }
  // A-frag weight pack: wa[((ks*64 + cout)*4 + q)*8 + j]
  //   ks = cc*3+kt; tap = kt*4+q; element = w[cout][ci=cc*8+j][tap] or 0 (pad)
  short* wa = (short*)(ws + WS_WA);
  for (int d = blockIdx.x * 256 + tid; d < 49152; d += 64 * 256) {
    int j = d & 7;
    int q = (d >> 3) & 3;
    int cout = (d >> 5) & 63;
    int ks = d >> 11;          // 0..23
    int kt = ks % 3;
    int cc = ks / 3;
    int tap = kt * 4 + q;
    short v = 0;
    if (tap < 9) {
      int ci = cc * 8 + j;
      int dy = tap / 3;
      int dx = tap - dy * 3;
      v = f2bf(conv_w[((cout * 64 + ci) * 3 + dy) * 3 + dx]);
    }
    wa[d] = v;
  }
}

// Merged conv + zero kernel. 512 threads.
// conv wgs: blockIdx < CONV_WGS, one 48x8 output strip each.
// zero wgs: fill inactive tiles (8 channels per wg).
__global__ __launch_bounds__(512, 4) void main_kernel(
    const float* __restrict__ x,
    const float* __restrict__ ws_f,
    const int* __restrict__ abi,
    float* __restrict__ out) {
  __shared__ __align__(16) short lds[3 * LDS_BUF];

  int b = blockIdx.x;
  int tid = threadIdx.x;

  if (b >= CONV_WGS) {
    // ---- zero path: inactive tiles ----
    const int* flags = (const int*)(ws_f + WS_FLAGS);
    int z = b - CONV_WGS;
    int tile = z >> 3;
    int part = z & 7;
    if (flags[tile]) return;
    int n = tile >> 8;
    int bh = (tile >> 4) & 15;
    int bw = tile & 15;
    float* base = out + (((n * 64 + part * 8) * 768 + bh * 48)) * 768 + bw * 48;
    float4 zv = make_float4(0.f, 0.f, 0.f, 0.f);
#pragma unroll
    for (int i = 0; i < 9; ++i) {        // 8ch*48r*12f4 = 4608
      int idx = i * 512 + tid;
      int f = idx % 12;
      int t2 = idx / 12;
      int rr = t2 % 48;
      int c = t2 / 48;                    // 0..7
      *((float4*)(base + (c * 768 + rr) * (size_t)768) + f) = zv;
    }
    return;
  }

  // ---- conv path ----
  int blk = b / 6;
  int strip = b - blk * 6;
  int n = abi[3 * blk + 0];
  int bh = abi[3 * blk + 1];
  int bw = abi[3 * blk + 2];
  int h0 = bh * 48 + strip * 8;   // output rows h0..h0+7
  int w0 = bw * 48;

  int lane = tid & 63;
  int wv = tid >> 6;              // wave 0..7 -> output row h0+wv
  int ln15 = lane & 15;
  int quad = lane >> 4;

  const float* xn = x + (size_t)n * 64 * 768 * 768;
  const short* wa = (const short*)(ws_f + WS_WA);
  const short* wap = wa + ln15 * 32 + quad * 8;

  // zero units for padded taps (u=570,588,606) in all 3 buffers
  if (tid < 8) {
#pragma unroll
    for (int bb = 0; bb < 3; ++bb) {
      lds[bb * LDS_BUF + 4560 + tid] = 0;
      lds[bb * LDS_BUF + 4704 + tid] = 0;
      lds[bb * LDS_BUF + 4848 + tid] = 0;
    }
  }

  // per-lane B-frag byte base per kt; +c16*288 walks c16 (u(c+16)=u(c)+18)
  int bA[3];
#pragma unroll
  for (int kt = 0; kt < 3; ++kt) {
    int tap = kt * 4 + quad;
    if (tap < 9) {
      int dy = tap / 3;
      int dx = tap - dy * 3;
      int cx = ln15 + dx;                       // 0..17 (c16=0 base)
      bA[kt] = ((wv + dy) * 57 + cx + (cx >> 3)) * 16;
    } else {
      bA[kt] = 9120;                            // zero unit 570; +288 -> 588,606
    }
  }

  // stage decode: e -> (f:14, r:10, ci:8); gw window [w0-4, w0+52)
  auto load_chunk = [&](int cc8, float4* pf) {
#pragma unroll
    for (int i = 0; i < 3; ++i) {
      int e = i * 512 + tid;
      float4 v = make_float4(0.f, 0.f, 0.f, 0.f);
      if (e < 1120) {
        int f = e % 14;
        int t = e / 14;
        int r = t % 10;
        int ci = t / 10;
        int gh = h0 - 1 + r;
        int gw0 = w0 - 4 + 4 * f;
        if ((unsigned)gh < 768u) {
          const float* rp = xn + ((size_t)(cc8 + ci) * 768 + gh) * 768;
          if (gw0 >= 0 && gw0 <= 764) {
            v = *(const float4*)(rp + gw0);
          } else {
#pragma unroll
            for (int j = 0; j < 4; ++j) {
              int gw = gw0 + j;
              if ((unsigned)gw < 768u) ((float*)&v)[j] = rp[gw];
            }
          }
        }
      }
      pf[i] = v;
    }
  };
  auto store_chunk = [&](short* dst, const float4* pf) {
#pragma unroll
    for (int i = 0; i < 3; ++i) {
      int e = i * 512 + tid;
      if (e < 1120) {
        int f = e % 14;
        int t = e / 14;
        int r = t % 10;
        int ci = t / 10;
        const float* vp = (const float*)&pf[i];
#pragma unroll
        for (int j = 0; j < 4; ++j) {
          int c = 4 * f - 3 + j;
          if ((unsigned)c < 50u) {
            int u = r * 57 + c + (c >> 3);      // skewed unit
            dst[u * 8 + ci] = f2bf(vp[j]);
          }
        }
      }
    }
  };

  float4 pf[3];
  // prologue: chunk 0 -> buf0 (one exposed vmcnt wait), then issue chunk 1
  load_chunk(0, pf);
  store_chunk(lds, pf);
  load_chunk(8, pf);

  floatx4 acc[3][4];
#pragma unroll
  for (int c16 = 0; c16 < 3; ++c16)
#pragma unroll
    for (int mt = 0; mt < 4; ++mt)
      acc[c16][mt] = (floatx4){0.f, 0.f, 0.f, 0.f};

  int rb = 0;                       // cc % 3
  for (int cc = 0; cc < 8; ++cc) {
    __syncthreads();                // separates store(cc)@prev iter from MFMA(cc)
    int sb = (rb == 2) ? 0 : rb + 1;
    if (cc < 7) store_chunk(lds + sb * LDS_BUF, pf);  // loads issued a full iter ago
    if (cc < 6) load_chunk((cc + 2) * 8, pf);         // re-feed the memory pipe
    const char* lb = (const char*)(lds + rb * LDS_BUF);
#pragma unroll
    for (int kt = 0; kt < 3; ++kt) {
      int ks = cc * 3 + kt;
      short8 af[4];
#pragma unroll
      for (int mt = 0; mt < 4; ++mt)
        af[mt] = *(const short8*)(wap + ks * 2048 + mt * 512);
#pragma unroll
      for (int c16 = 0; c16 < 3; ++c16) {
        short8 bf = *(const short8*)(lb + bA[kt] + c16 * 288);
#pragma unroll
        for (int mt = 0; mt < 4; ++mt)
          acc[c16][mt] = __builtin_amdgcn_mfma_f32_16x16x32_bf16(
              af[mt], bf, acc[c16][mt], 0, 0, 0);
      }
    }
    rb = sb;
  }

  // ---- epilogue: BN fold + ReLU + store ----
  // D layout: row(m=cout within tile) = quad*4+reg, col(n=pixel) = ln15
  const float* scale = ws_f + WS_SCALE;
  const float* shift = ws_f + WS_SHIFT;
  float* op = out + (size_t)n * 64 * 768 * 768 + (size_t)(h0 + wv) * 768 + (w0 + ln15);
#pragma unroll
  for (int mt = 0; mt < 4; ++mt) {
#pragma unroll
    for (int reg = 0; reg < 4; ++reg) {
      int cout = mt * 16 + quad * 4 + reg;
      float sc = scale[cout];
      float sh = shift[cout];
#pragma unroll
      for (int c16 = 0; c16 < 3; ++c16) {
        float vv = fmaf(acc[c16][mt][reg], sc, sh);
        vv = vv > 0.f ? vv : 0.f;
        op[(size_t)cout * 589824 + c16 * 16] = vv;
      }
    }
  }
}

extern "C" void kernel_launch(void* const* d_in, const int* in_sizes, int n_in,
                              void* d_out, int out_size, void* d_ws, size_t ws_size,
                              hipStream_t stream) {
  const float* x = (const float*)d_in[0];
  const float* conv_w = (const float*)d_in[1];
  const float* conv_b = (const float*)d_in[2];
  const float* gamma = (const float*)d_in[3];
  const float* beta = (const float*)d_in[4];
  const float* run_mean = (const float*)d_in[5];
  const float* run_var = (const float*)d_in[6];
  const int* abi = (const int*)d_in[7];
  float* out = (float*)d_out;
  float* ws = (float*)d_ws;

  prep_kernel<<<64, 256, 0, stream>>>(conv_w, conv_b, gamma, beta,
                                      run_mean, run_var, abi, ws);
  main_kernel<<<CONV_WGS + ZERO_WGS, 512, 0, stream>>>(x, ws, abi, out);
}

// Round 4
// 558.030 us; speedup vs baseline: 1.8592x; 1.0491x over previous
//
#include <hip/hip_runtime.h>

// SparseBlock Conv2d+BN+ReLU. N=2, CIN=COUT=64, H=W=768, K=3, pad=1,
// 256 active 48x48 blocks (stride 48), output zeroed elsewhere.
//
// R4: weights out of the MFMA critical path. Previously af fragments were
// global_load_dwordx4 from ws inside the inner loop (12/lane/iter, vmcnt on
// the MFMA chain, 384 KB/CU/iter through L1). Now prep packs wa in DMA-linear
// order and main stages the 12.3KB per-chunk slice into LDS via
// global_load_lds (fire-and-forget, 0 VGPRs), double-buffered one iter ahead;
// af becomes conflict-free ds_read_b128. Input staging back to 2 buffers
// (R3's 3rd buffer was worth only ~3%) to fit 44KB LDS -> 3 wgs/CU.
// R2 lesson: keep conv wgs first in dispatch order (interleave = tail).
// R1 lesson: keep lb(512,4); forcing VGPR 32 caused scratch spill (5x traffic).

typedef __attribute__((ext_vector_type(8))) short short8;
typedef __attribute__((ext_vector_type(4))) float floatx4;

// ws layout (float slots):
// [0,64)    scale
// [64,128)  shift
// [128,640) flags (512 ints)
// [640,..)  wa: 49152 bf16 weights, DMA-linear:
//           slot g = ((cc*3+kt)*4+mt)*64 + (ln15*4+quad), 8 shorts/slot:
//           j -> w[cout=mt*16+ln15][ci=cc*8+j][tap=kt*4+quad], 0 if tap>=9.
#define WS_SCALE 0
#define WS_SHIFT 64
#define WS_FLAGS 128
#define WS_WA    640

#define CONV_WGS 1536   // 256 blocks * 6 strips
#define ZERO_WGS 4096   // 512 tiles * 8 channel-parts

// skewed bf16 input tile: 16B unit u(r,c) = r*57 + c + (c>>3); short idx u*8+ci.
// data units u<=568; zero units 570,588,606 serve padded taps.
#define LDS_BUF 4864    // shorts per input buffer
#define WSLICE  6144    // shorts per weight slice (3kt * 4mt * 64 units * 8)

__device__ __forceinline__ short f2bf(float f) {
  unsigned u = __builtin_bit_cast(unsigned, f);
  u += 0x7fffu + ((u >> 16) & 1u);
  return (short)(u >> 16);
}

__global__ __launch_bounds__(256) void prep_kernel(
    const float* __restrict__ conv_w,
    const float* __restrict__ conv_b,
    const float* __restrict__ gamma,
    const float* __restrict__ beta,
    const float* __restrict__ run_mean,
    const float* __restrict__ run_var,
    const int* __restrict__ abi,
    float* __restrict__ ws) {
  int tid = threadIdx.x;
  if (blockIdx.x == 0) {
    int* flags = (int*)(ws + WS_FLAGS);
    flags[tid] = 0;
    flags[tid + 256] = 0;
    __syncthreads();
    int n = abi[3 * tid + 0];
    int bh = abi[3 * tid + 1];
    int bw = abi[3 * tid + 2];
    flags[n * 256 + bh * 16 + bw] = 1;
    if (tid < 64) {
      float inv = gamma[tid] * rsqrtf(run_var[tid] + 1e-3f);
      ws[WS_SCALE + tid] = inv;
      ws[WS_SHIFT + tid] = (conv_b[tid] - run_mean[tid]) * inv + beta[tid];
    }
  }
  // DMA-linear weight pack (see header comment).
  short* wa = (short*)(ws + WS_WA);
  for (int d = blockIdx.x * 256 + tid; d < 49152; d += 64 * 256) {
    int j = d & 7;
    int g = d >> 3;            // slot 0..6143
    int i4q = g & 63;
    int ln15 = i4q >> 2;
    int quad = i4q & 3;
    int mt = (g >> 6) & 3;
    int ks = g >> 8;           // 0..23
    int kt = ks % 3;
    int cc = ks / 3;
    int tap = kt * 4 + quad;
    short v = 0;
    if (tap < 9) {
      int cout = mt * 16 + ln15;
      int ci = cc * 8 + j;
      int dy = tap / 3;
      int dx = tap - dy * 3;
      v = f2bf(conv_w[((cout * 64 + ci) * 3 + dy) * 3 + dx]);
    }
    wa[d] = v;
  }
}

// Merged conv + zero kernel. 512 threads.
__global__ __launch_bounds__(512, 4) void main_kernel(
    const float* __restrict__ x,
    const float* __restrict__ ws_f,
    const int* __restrict__ abi,
    float* __restrict__ out) {
  __shared__ __align__(16) short lds_i[2][LDS_BUF];
  __shared__ __align__(16) short lds_w[2][WSLICE];

  int b = blockIdx.x;
  int tid = threadIdx.x;

  if (b >= CONV_WGS) {
    // ---- zero path: inactive tiles ----
    const int* flags = (const int*)(ws_f + WS_FLAGS);
    int z = b - CONV_WGS;
    int tile = z >> 3;
    int part = z & 7;
    if (flags[tile]) return;
    int n = tile >> 8;
    int bh = (tile >> 4) & 15;
    int bw = tile & 15;
    float* base = out + (((n * 64 + part * 8) * 768 + bh * 48)) * 768 + bw * 48;
    float4 zv = make_float4(0.f, 0.f, 0.f, 0.f);
#pragma unroll
    for (int i = 0; i < 9; ++i) {        // 8ch*48r*12f4 = 4608
      int idx = i * 512 + tid;
      int f = idx % 12;
      int t2 = idx / 12;
      int rr = t2 % 48;
      int c = t2 / 48;                    // 0..7
      *((float4*)(base + (c * 768 + rr) * (size_t)768) + f) = zv;
    }
    return;
  }

  // ---- conv path ----
  int blk = b / 6;
  int strip = b - blk * 6;
  int n = abi[3 * blk + 0];
  int bh = abi[3 * blk + 1];
  int bw = abi[3 * blk + 2];
  int h0 = bh * 48 + strip * 8;   // output rows h0..h0+7
  int w0 = bw * 48;

  int lane = tid & 63;
  int wv = tid >> 6;              // wave 0..7 -> output row h0+wv
  int ln15 = lane & 15;
  int quad = lane >> 4;

  const float* xn = x + (size_t)n * 64 * 768 * 768;
  const short* wa = (const short*)(ws_f + WS_WA);
  int wOff = (ln15 * 4 + quad) * 8;   // per-lane weight-unit short offset

  // zero units for padded taps (u=570,588,606) in both input buffers
  if (tid < 8) {
#pragma unroll
    for (int bb = 0; bb < 2; ++bb) {
      lds_i[bb][4560 + tid] = 0;
      lds_i[bb][4704 + tid] = 0;
      lds_i[bb][4848 + tid] = 0;
    }
  }

  // per-lane B-frag byte base per kt; +c16*288 walks c16 (u(c+16)=u(c)+18)
  int bA[3];
#pragma unroll
  for (int kt = 0; kt < 3; ++kt) {
    int tap = kt * 4 + quad;
    if (tap < 9) {
      int dy = tap / 3;
      int dx = tap - dy * 3;
      int cx = ln15 + dx;                       // 0..17 (c16=0 base)
      bA[kt] = ((wv + dy) * 57 + cx + (cx >> 3)) * 16;
    } else {
      bA[kt] = 9120;                            // zero unit 570; +288 -> 588,606
    }
  }

  // weight slice DMA: 768 slots x 16B, linear by lane (fire-and-forget)
  auto wload = [&](int cc, int wsel) {
    const short* src = wa + (size_t)cc * WSLICE;
    __builtin_amdgcn_global_load_lds(
        (const __attribute__((address_space(1))) void*)(src + tid * 8),
        (__attribute__((address_space(3))) void*)&lds_w[wsel][tid * 8], 16, 0, 0);
    if (tid < 256)
      __builtin_amdgcn_global_load_lds(
          (const __attribute__((address_space(1))) void*)(src + 4096 + tid * 8),
          (__attribute__((address_space(3))) void*)&lds_w[wsel][4096 + tid * 8],
          16, 0, 0);
  };

  // stage decode: e -> (f:14, r:10, ci:8); gw window [w0-4, w0+52)
  auto load_chunk = [&](int cc8, float4* pf) {
#pragma unroll
    for (int i = 0; i < 3; ++i) {
      int e = i * 512 + tid;
      float4 v = make_float4(0.f, 0.f, 0.f, 0.f);
      if (e < 1120) {
        int f = e % 14;
        int t = e / 14;
        int r = t % 10;
        int ci = t / 10;
        int gh = h0 - 1 + r;
        int gw0 = w0 - 4 + 4 * f;
        if ((unsigned)gh < 768u) {
          const float* rp = xn + ((size_t)(cc8 + ci) * 768 + gh) * 768;
          if (gw0 >= 0 && gw0 <= 764) {
            v = *(const float4*)(rp + gw0);
          } else {
#pragma unroll
            for (int j = 0; j < 4; ++j) {
              int gw = gw0 + j;
              if ((unsigned)gw < 768u) ((float*)&v)[j] = rp[gw];
            }
          }
        }
      }
      pf[i] = v;
    }
  };
  auto store_chunk = [&](short* dst, const float4* pf) {
#pragma unroll
    for (int i = 0; i < 3; ++i) {
      int e = i * 512 + tid;
      if (e < 1120) {
        int f = e % 14;
        int t = e / 14;
        int r = t % 10;
        int ci = t / 10;
        const float* vp = (const float*)&pf[i];
#pragma unroll
        for (int j = 0; j < 4; ++j) {
          int c = 4 * f - 3 + j;
          if ((unsigned)c < 50u) {
            int u = r * 57 + c + (c >> 3);      // skewed unit
            dst[u * 8 + ci] = f2bf(vp[j]);
          }
        }
      }
    }
  };

  float4 pf[3];
  // prologue: weights(0) DMA; input chunk 0 -> regs -> ibuf0; input chunk 1 -> regs
  wload(0, 0);
  load_chunk(0, pf);
  store_chunk(lds_i[0], pf);
  load_chunk(8, pf);

  floatx4 acc[3][4];
#pragma unroll
  for (int c16 = 0; c16 < 3; ++c16)
#pragma unroll
    for (int mt = 0; mt < 4; ++mt)
      acc[c16][mt] = (floatx4){0.f, 0.f, 0.f, 0.f};

  __syncthreads();   // drains wload(0) DMA + ibuf0 ds_writes

  for (int cc = 0; cc < 8; ++cc) {
    int bsel = cc & 1;
    if (cc < 7) {
      wload(cc + 1, bsel ^ 1);                  // DMA first (no reg deps)
      store_chunk(lds_i[bsel ^ 1], pf);         // regs loaded last iter
    }
    if (cc < 6) load_chunk((cc + 2) * 8, pf);
    const char* lb = (const char*)lds_i[bsel];
    const short* lw = lds_w[bsel];
#pragma unroll
    for (int kt = 0; kt < 3; ++kt) {
      short8 af[4];
#pragma unroll
      for (int mt = 0; mt < 4; ++mt)
        af[mt] = *(const short8*)(lw + wOff + ((kt * 4 + mt) << 9));
#pragma unroll
      for (int c16 = 0; c16 < 3; ++c16) {
        short8 bf = *(const short8*)(lb + bA[kt] + c16 * 288);
#pragma unroll
        for (int mt = 0; mt < 4; ++mt)
          acc[c16][mt] = __builtin_amdgcn_mfma_f32_16x16x32_bf16(
              af[mt], bf, acc[c16][mt], 0, 0, 0);
      }
    }
    if (cc < 7) __syncthreads();   // drains DMA(cc+1) + ds_writes(cc+1)
  }

  // ---- epilogue: BN fold + ReLU + store ----
  // D layout: row(m=cout within tile) = quad*4+reg, col(n=pixel) = ln15
  const float* scale = ws_f + WS_SCALE;
  const float* shift = ws_f + WS_SHIFT;
  float* op = out + (size_t)n * 64 * 768 * 768 + (size_t)(h0 + wv) * 768 + (w0 + ln15);
#pragma unroll
  for (int mt = 0; mt < 4; ++mt) {
#pragma unroll
    for (int reg = 0; reg < 4; ++reg) {
      int cout = mt * 16 + quad * 4 + reg;
      float sc = scale[cout];
      float sh = shift[cout];
#pragma unroll
      for (int c16 = 0; c16 < 3; ++c16) {
        float vv = fmaf(acc[c16][mt][reg], sc, sh);
        vv = vv > 0.f ? vv : 0.f;
        op[(size_t)cout * 589824 + c16 * 16] = vv;
      }
    }
  }
}

extern "C" void kernel_launch(void* const* d_in, const int* in_sizes, int n_in,
                              void* d_out, int out_size, void* d_ws, size_t ws_size,
                              hipStream_t stream) {
  const float* x = (const float*)d_in[0];
  const float* conv_w = (const float*)d_in[1];
  const float* conv_b = (const float*)d_in[2];
  const float* gamma = (const float*)d_in[3];
  const float* beta = (const float*)d_in[4];
  const float* run_mean = (const float*)d_in[5];
  const float* run_var = (const float*)d_in[6];
  const int* abi = (const int*)d_in[7];
  float* out = (float*)d_out;
  float* ws = (float*)d_ws;

  prep_kernel<<<64, 256, 0, stream>>>(conv_w, conv_b, gamma, beta,
                                      run_mean, run_var, abi, ws);
  main_kernel<<<CONV_WGS + ZERO_WGS, 512, 0, stream>>>(x, ws, abi, out);
}